// Round 7
// baseline (215.499 us; speedup 1.0000x reference)
//
#include <hip/hip_runtime.h>
#include <cstdint>

typedef _Float16 f16;
typedef _Float16 f16x2 __attribute__((ext_vector_type(2)));
typedef _Float16 f16x4 __attribute__((ext_vector_type(4)));
typedef _Float16 f16x8 __attribute__((ext_vector_type(8)));
typedef float f32x4 __attribute__((ext_vector_type(4)));
typedef float f32x16 __attribute__((ext_vector_type(16)));
typedef int i32x4 __attribute__((ext_vector_type(4)));

#define MFMA16(a, b, c) __builtin_amdgcn_mfma_f32_16x16x32_f16(a, b, c, 0, 0, 0)
#define MFMA32(a, b, c) __builtin_amdgcn_mfma_f32_32x32x16_f16(a, b, c, 0, 0, 0)
#define LOG2E 1.4426950408889634f

// direct global->LDS 16B async copy (m97 pattern)
__device__ __forceinline__ void gload_lds16(const void* g, void* l) {
    __builtin_amdgcn_global_load_lds((__attribute__((address_space(1))) void*)(g),
                                     (__attribute__((address_space(3))) void*)(l),
                                     16, 0, 0);
}

__device__ __forceinline__ int pk2(float a, float b) {
    f16x2 t = {(f16)a, (f16)b};
    return __builtin_bit_cast(int, t);
}

// Problem constants: S=2048, B=2, D=1024, H=16, DK=64
// ws layout (bytes):
//  vt   @ 0         : [32][64][2048] f16 = 8 MB  (V transposed; reuses xh after gemm_qkv)
//  xh   @ 0         : 4096x1024 f16 = 8 MB       (dead after gemm_qkv)
//  wqh  @ 8388608   : 3072x1024 f16 = 6 MB
//  woh  @ 14680064  : 1024x1024 f16 = 2 MB
//  qh   @ 16777216  : [32][2048][64] f16 = 8 MB  (PRE-SCALED by 0.125)
//  kh   @ 25165824  : [32][2048][64] f16 = 8 MB
//  vh   @ 33554432  : [32][2048][64] f16 = 8 MB  (V row layout, from gemm)
//  ah   @ 41943040  : [4096][1024] f16 = 8 MB

// Single fused cast: outputs are contiguous in ws (xh | wqh | woh).
__global__ void cast_all(const float* __restrict__ x, const float* __restrict__ wqv,
                         const float* __restrict__ wo, f16* __restrict__ out) {
    int i = blockIdx.x * blockDim.x + threadIdx.x;  // 0..2097151 float4s
    const float* src; int li;
    if (i < 1048576)      { src = x;   li = i; }
    else if (i < 1835008) { src = wqv; li = i - 1048576; }
    else                  { src = wo;  li = i - 1835008; }
    float4 v = reinterpret_cast<const float4*>(src)[li];
    f16x4 o = {(f16)v.x, (f16)v.y, (f16)v.z, (f16)v.w};
    reinterpret_cast<f16x4*>(out)[i] = o;
}

// ---------------- QKV GEMM: C[4096x3072] = X[4096x1024] * Wqkv^T ----------------
// BK=64, XOR-swizzled 16B units (row stride 128B = 32 banks).
__global__ __launch_bounds__(256) void gemm_qkv(
    const f16* __restrict__ A, const f16* __restrict__ B,
    f16* __restrict__ outq, f16* __restrict__ outk, f16* __restrict__ outv)
{
    __shared__ f16 As[128 * 64];
    __shared__ f16 Bs[128 * 64];
    const int tid = threadIdx.x;
    const int lane = tid & 63;
    const int wave = tid >> 6;
    const int wm = wave >> 1, wn = wave & 1;
    const int bm = blockIdx.y * 128, bn = blockIdx.x * 128;
    const int sr = tid >> 3;                 // staging row 0..31 (per 32-row issue)
    const int scu = (tid & 7) ^ (sr & 7);    // swizzled global 16B-unit
    const int fr = lane & 15, fq = lane >> 4;
    const int u0 = (fq ^ (fr & 7)) * 8;
    const int u1 = ((4 + fq) ^ (fr & 7)) * 8;

    f32x4 acc[4][4] = {};

    for (int k0 = 0; k0 < 1024; k0 += 64) {
        __syncthreads();
#pragma unroll
        for (int is = 0; is < 4; ++is) {
            gload_lds16(&A[(bm + sr + is * 32) * 1024 + k0 + scu * 8], &As[is * 2048 + tid * 8]);
            gload_lds16(&B[(bn + sr + is * 32) * 1024 + k0 + scu * 8], &Bs[is * 2048 + tid * 8]);
        }
        __syncthreads();
        f16x8 af0[4], af1[4], bf0[4], bf1[4];
#pragma unroll
        for (int mt = 0; mt < 4; ++mt) {
            int r = wm * 64 + mt * 16 + fr;
            af0[mt] = *(const f16x8*)&As[r * 64 + u0];
            af1[mt] = *(const f16x8*)&As[r * 64 + u1];
        }
#pragma unroll
        for (int nt = 0; nt < 4; ++nt) {
            int r = wn * 64 + nt * 16 + fr;
            bf0[nt] = *(const f16x8*)&Bs[r * 64 + u0];
            bf1[nt] = *(const f16x8*)&Bs[r * 64 + u1];
        }
#pragma unroll
        for (int mt = 0; mt < 4; ++mt)
#pragma unroll
            for (int nt = 0; nt < 4; ++nt) {
                acc[mt][nt] = MFMA16(af0[mt], bf0[nt], acc[mt][nt]);
                acc[mt][nt] = MFMA16(af1[mt], bf1[nt], acc[mt][nt]);
            }
    }

#pragma unroll
    for (int mt = 0; mt < 4; ++mt)
#pragma unroll
        for (int nt = 0; nt < 4; ++nt)
#pragma unroll
            for (int i = 0; i < 4; ++i) {
                int row = bm + wm * 64 + mt * 16 + fq * 4 + i;  // (s*2+b)
                int col = bn + wn * 64 + nt * 16 + fr;          // e in [0,3072)
                int s = row >> 1, b = row & 1;
                int which = col >> 10, rem = col & 1023;
                int h = rem >> 6, dk = rem & 63;
                int bh = b * 16 + h;
                float va = acc[mt][nt][i];
                if (which == 0)      outq[(bh * 2048 + s) * 64 + dk] = (f16)(va * 0.125f);
                else if (which == 1) outk[(bh * 2048 + s) * 64 + dk] = (f16)va;
                else                 outv[(bh * 2048 + s) * 64 + dk] = (f16)va;
            }
}

// ---------------- V transpose: [bh][s][dk] -> [bh][dk][s] ----------------
__global__ __launch_bounds__(256) void transpose_v(const f16* __restrict__ v, f16* __restrict__ vt) {
    __shared__ f16 T[64 * 72];
    const int tid = threadIdx.x;
    const int bh = blockIdx.y;
    const int s0 = blockIdx.x * 64;
    const f16* V = v + (bh * 2048 + s0) * 64;
    const int u = tid & 7;
#pragma unroll
    for (int hh = 0; hh < 2; ++hh) {
        int r = (tid >> 3) + hh * 32;   // s-local
        *(f16x8*)&T[r * 72 + u * 8] = *(const f16x8*)&V[r * 64 + u * 8];
    }
    __syncthreads();
#pragma unroll
    for (int o = 0; o < 2; ++o) {
        int dk = (tid >> 3) + o * 32;
        f16x8 val;
#pragma unroll
        for (int j = 0; j < 8; ++j) val[j] = T[(u * 8 + j) * 72 + dk];
        *(f16x8*)&vt[(bh * 64 + dk) * 2048 + s0 + u * 8] = val;
    }
}

// ---------------- Flash attention (causal, no-max softmax), 32x32 MFMA ----------------
// Block = 2 waves = 64 q-rows (wave = 32 rows). Grid (32 qb x 32 bh) = 1024 blocks,
// longest-first for backfill balance. 64-key chunks double-buffered in LDS.
// S^T = K·Q^T (A=K from LDS, B=Q regs); P^T -> PV B-operand via pack+shfl_xor(32)
// (no LDS round-trip); O^T = VT·P^T in C-layout (row=dk, col=q).
__global__ __launch_bounds__(128) void attn_kernel(
    const f16* __restrict__ qg, const f16* __restrict__ kg,
    const f16* __restrict__ vtg, f16* __restrict__ attn)
{
    __shared__ f16 Ks[2][64 * 64];
    __shared__ f16 Vs[2][64 * 64];
    const int tid = threadIdx.x;            // 0..127
    const int lane = tid & 63;
    const int wave = tid >> 6;              // 0,1
    const int qb = 31 - (int)blockIdx.x;    // 64-row q block, longest first
    const int bh = blockIdx.y;
    const int b = bh >> 4, h = bh & 15;
    const int col = lane & 31;              // q-local (C col)
    const int H = lane >> 5;                // wave half
    const int qrow0 = qb * 64 + wave * 32;
    const int qmax = qrow0 + 31;

    const f16* Q  = qg  + bh * 2048 * 64;
    const f16* K  = kg  + bh * 2048 * 64;
    const f16* VT = vtg + bh * 64 * 2048;

    const int sr = tid >> 3;                // 0..15 staging row within issue
    const int sj = tid & 7;
    const int scu = sj ^ (sr & 7);          // swizzled 16B-unit (key = row&7; issues step rows by 16)

    // Q as B-operand fragments: B[n=q=col][k = c*16 + H*8 + j]
    f16x8 qf[4];
#pragma unroll
    for (int c = 0; c < 4; ++c)
        qf[c] = *(const f16x8*)&Q[(qrow0 + col) * 64 + c * 16 + H * 8];

    f32x16 oT[2] = {};
    float li = 0.f;

    auto stage = [&](int kc, int buf) {
        const int kb = kc * 64;
#pragma unroll
        for (int i = 0; i < 4; ++i) {
            gload_lds16(&K[(kb + i * 16 + sr) * 64 + scu * 8],   &Ks[buf][i * 1024 + tid * 8]);
            gload_lds16(&VT[(i * 16 + sr) * 2048 + kb + scu * 8], &Vs[buf][i * 1024 + tid * 8]);
        }
    };

    const int nc = qb + 1;
    stage(0, 0);
    for (int kc = 0; kc < nc; ++kc) {
        const int kb = kc * 64;
        const int cur = kc & 1;
        __syncthreads();
        if (kc + 1 < nc) stage(kc + 1, cur ^ 1);
        const f16* Kb = Ks[cur];
        const f16* Vb = Vs[cur];

#pragma unroll
        for (int kt = 0; kt < 2; ++kt) {
            const int kt0 = kb + kt * 32;
            if (kt0 > qmax) continue;   // tile fully masked (wave-uniform)

            // S^T tile: rows=keys kt0..kt0+31, cols=q
            f32x16 sc = {};
#pragma unroll
            for (int c = 0; c < 4; ++c) {
                int r = kt * 32 + col;
                f16x8 ak = *(const f16x8*)&Kb[r * 64 + (((c * 2 + H) ^ (r & 7)) * 8)];
                sc = MFMA32(ak, qf[c], sc);
            }
            if (kt0 + 31 > qrow0) {     // partial causal mask
                int q = qrow0 + col;
#pragma unroll
                for (int r = 0; r < 16; ++r) {
                    int key = kt0 + (r & 3) + 8 * (r >> 2) + 4 * H;
                    if (key > q) sc[r] = -1e30f;
                }
            }
            // exp2 + li partials
#pragma unroll
            for (int r = 0; r < 16; ++r) {
                float p = __builtin_amdgcn_exp2f(sc[r] * LOG2E);
                li += p;
                sc[r] = p;
            }
            // pack + cross-half exchange -> PV B-fragments
            int pk[8], xk[8];
#pragma unroll
            for (int g = 0; g < 8; ++g) pk[g] = pk2(sc[2 * g], sc[2 * g + 1]);
#pragma unroll
            for (int g = 0; g < 8; ++g) xk[g] = __shfl_xor(pk[g], 32);
#pragma unroll
            for (int c2 = 0; c2 < 2; ++c2) {
                i32x4 bi;
                bi.x = H ? xk[4 * c2 + 2] : pk[4 * c2];
                bi.y = H ? xk[4 * c2 + 3] : pk[4 * c2 + 1];
                bi.z = H ? pk[4 * c2 + 2] : xk[4 * c2];
                bi.w = H ? pk[4 * c2 + 3] : xk[4 * c2 + 1];
                f16x8 pb = __builtin_bit_cast(f16x8, bi);
                const int sub = kt * 2 + c2;
#pragma unroll
                for (int dt = 0; dt < 2; ++dt) {
                    int rv = dt * 32 + col;
                    f16x8 av = *(const f16x8*)&Vb[rv * 64 + (((sub * 2 + H) ^ (rv & 7)) * 8)];
                    oT[dt] = MFMA32(av, pb, oT[dt]);
                }
            }
        }
    }

    // epilogue: li(q) spread across lane pair (col, col+32)
    li += __shfl_xor(li, 32);
    float inv = __builtin_amdgcn_rcpf(li);
    const int q = qrow0 + col;
    f16* dst = &attn[(q * 2 + b) * 1024 + h * 64];
#pragma unroll
    for (int dt = 0; dt < 2; ++dt)
#pragma unroll
        for (int g = 0; g < 4; ++g) {
            f16x4 pv = {(f16)(oT[dt][4 * g] * inv),     (f16)(oT[dt][4 * g + 1] * inv),
                        (f16)(oT[dt][4 * g + 2] * inv), (f16)(oT[dt][4 * g + 3] * inv)};
            *(f16x4*)&dst[dt * 32 + 8 * g + 4 * H] = pv;
        }
}

// ---------------- Out GEMM: out[4096x1024] = A[4096x1024] * Wout^T + bias ----------------
__global__ __launch_bounds__(256) void gemm_out(
    const f16* __restrict__ A, const f16* __restrict__ B,
    const float* __restrict__ bias, float* __restrict__ out)
{
    __shared__ f16 As[128 * 64];
    __shared__ f16 Bs[64 * 64];
    const int tid = threadIdx.x;
    const int lane = tid & 63;
    const int wave = tid >> 6;
    const int wm = wave >> 1, wn = wave & 1;
    const int bm = blockIdx.y * 128, bn = blockIdx.x * 64;
    const int sr = tid >> 3;
    const int scu = (tid & 7) ^ (sr & 7);
    const int fr = lane & 15, fq = lane >> 4;
    const int u0 = (fq ^ (fr & 7)) * 8;
    const int u1 = ((4 + fq) ^ (fr & 7)) * 8;

    f32x4 acc[4][2] = {};

    for (int k0 = 0; k0 < 1024; k0 += 64) {
        __syncthreads();
#pragma unroll
        for (int is = 0; is < 4; ++is)
            gload_lds16(&A[(bm + sr + is * 32) * 1024 + k0 + scu * 8], &As[is * 2048 + tid * 8]);
#pragma unroll
        for (int is = 0; is < 2; ++is)
            gload_lds16(&B[(bn + sr + is * 32) * 1024 + k0 + scu * 8], &Bs[is * 2048 + tid * 8]);
        __syncthreads();
        f16x8 af0[4], af1[4], bf0[2], bf1[2];
#pragma unroll
        for (int mt = 0; mt < 4; ++mt) {
            int r = wm * 64 + mt * 16 + fr;
            af0[mt] = *(const f16x8*)&As[r * 64 + u0];
            af1[mt] = *(const f16x8*)&As[r * 64 + u1];
        }
#pragma unroll
        for (int nt = 0; nt < 2; ++nt) {
            int r = wn * 32 + nt * 16 + fr;
            bf0[nt] = *(const f16x8*)&Bs[r * 64 + u0];
            bf1[nt] = *(const f16x8*)&Bs[r * 64 + u1];
        }
#pragma unroll
        for (int mt = 0; mt < 4; ++mt)
#pragma unroll
            for (int nt = 0; nt < 2; ++nt) {
                acc[mt][nt] = MFMA16(af0[mt], bf0[nt], acc[mt][nt]);
                acc[mt][nt] = MFMA16(af1[mt], bf1[nt], acc[mt][nt]);
            }
    }

#pragma unroll
    for (int mt = 0; mt < 4; ++mt)
#pragma unroll
        for (int nt = 0; nt < 2; ++nt)
#pragma unroll
            for (int i = 0; i < 4; ++i) {
                int row = bm + wm * 64 + mt * 16 + fq * 4 + i;
                int col = bn + wn * 32 + nt * 16 + fr;
                out[row * 1024 + col] = acc[mt][nt][i] + bias[col];
            }
}

extern "C" void kernel_launch(void* const* d_in, const int* in_sizes, int n_in,
                              void* d_out, int out_size, void* d_ws, size_t ws_size,
                              hipStream_t stream)
{
    const float* x     = (const float*)d_in[0];
    const float* w_qkv = (const float*)d_in[1];
    const float* w_out = (const float*)d_in[2];
    const float* b_out = (const float*)d_in[3];
    float* out = (float*)d_out;

    char* ws = (char*)d_ws;
    f16* xh  = (f16*)(ws);              // dead after gemm_qkv
    f16* vt  = (f16*)(ws);              // reuses xh space
    f16* wqh = (f16*)(ws + 8388608);
    f16* woh = (f16*)(ws + 14680064);
    f16* qh  = (f16*)(ws + 16777216);
    f16* kh  = (f16*)(ws + 25165824);
    f16* vh  = (f16*)(ws + 33554432);
    f16* ah  = (f16*)(ws + 41943040);

    cast_all<<<8192, 256, 0, stream>>>(x, w_qkv, w_out, xh);
    gemm_qkv<<<dim3(24, 32), 256, 0, stream>>>(xh, wqh, qh, kh, vh);
    transpose_v<<<dim3(32, 32), 256, 0, stream>>>(vh, vt);
    attn_kernel<<<dim3(32, 32), 128, 0, stream>>>(qh, kh, vt, ah);
    gemm_out<<<dim3(16, 32), 256, 0, stream>>>(ah, woh, b_out, out);
}

// Round 8
// 206.505 us; speedup vs baseline: 1.0436x; 1.0436x over previous
//
#include <hip/hip_runtime.h>
#include <cstdint>

typedef _Float16 f16;
typedef _Float16 f16x2 __attribute__((ext_vector_type(2)));
typedef _Float16 f16x4 __attribute__((ext_vector_type(4)));
typedef _Float16 f16x8 __attribute__((ext_vector_type(8)));
typedef float f32x4 __attribute__((ext_vector_type(4)));
typedef float f32x16 __attribute__((ext_vector_type(16)));
typedef int i32x4 __attribute__((ext_vector_type(4)));

#define MFMA16(a, b, c) __builtin_amdgcn_mfma_f32_16x16x32_f16(a, b, c, 0, 0, 0)
#define MFMA32(a, b, c) __builtin_amdgcn_mfma_f32_32x32x16_f16(a, b, c, 0, 0, 0)
#define QSCALE 0.1803368801111243f  /* 0.125 * log2(e): scores land in log2 domain */

// direct global->LDS 16B async copy (m97 pattern)
__device__ __forceinline__ void gload_lds16(const void* g, void* l) {
    __builtin_amdgcn_global_load_lds((__attribute__((address_space(1))) void*)(g),
                                     (__attribute__((address_space(3))) void*)(l),
                                     16, 0, 0);
}

__device__ __forceinline__ int pk2(float a, float b) {
    f16x2 t = {(f16)a, (f16)b};
    return __builtin_bit_cast(int, t);
}

// Problem constants: S=2048, B=2, D=1024, H=16, DK=64
// ws layout (bytes):
//  vt   @ 0         : [32][64][2048] f16 = 8 MB  (V transposed; reuses xh after gemm_qkv)
//  xh   @ 0         : 4096x1024 f16 = 8 MB       (dead after gemm_qkv)
//  wqh  @ 8388608   : 3072x1024 f16 = 6 MB
//  woh  @ 14680064  : 1024x1024 f16 = 2 MB
//  qh   @ 16777216  : [32][2048][64] f16 = 8 MB  (PRE-SCALED by 0.125*log2e)
//  kh   @ 25165824  : [32][2048][64] f16 = 8 MB
//  vh   @ 33554432  : [32][2048][64] f16 = 8 MB  (V row layout, from gemm)
//  ah   @ 41943040  : [4096][1024] f16 = 8 MB

// Single fused cast: outputs are contiguous in ws (xh | wqh | woh).
__global__ void cast_all(const float* __restrict__ x, const float* __restrict__ wqv,
                         const float* __restrict__ wo, f16* __restrict__ out) {
    int i = blockIdx.x * blockDim.x + threadIdx.x;  // 0..2097151 float4s
    const float* src; int li;
    if (i < 1048576)      { src = x;   li = i; }
    else if (i < 1835008) { src = wqv; li = i - 1048576; }
    else                  { src = wo;  li = i - 1835008; }
    float4 v = reinterpret_cast<const float4*>(src)[li];
    f16x4 o = {(f16)v.x, (f16)v.y, (f16)v.z, (f16)v.w};
    reinterpret_cast<f16x4*>(out)[i] = o;
}

// ---------------- QKV GEMM: C[4096x3072] = X[4096x1024] * Wqkv^T ----------------
// BK=64, XOR-swizzled 16B units (row stride 128B = 32 banks).
__global__ __launch_bounds__(256) void gemm_qkv(
    const f16* __restrict__ A, const f16* __restrict__ B,
    f16* __restrict__ outq, f16* __restrict__ outk, f16* __restrict__ outv)
{
    __shared__ f16 As[128 * 64];
    __shared__ f16 Bs[128 * 64];
    const int tid = threadIdx.x;
    const int lane = tid & 63;
    const int wave = tid >> 6;
    const int wm = wave >> 1, wn = wave & 1;
    const int bm = blockIdx.y * 128, bn = blockIdx.x * 128;
    const int sr = tid >> 3;                 // staging row 0..31 (per 32-row issue)
    const int scu = (tid & 7) ^ (sr & 7);    // swizzled global 16B-unit
    const int fr = lane & 15, fq = lane >> 4;
    const int u0 = (fq ^ (fr & 7)) * 8;
    const int u1 = ((4 + fq) ^ (fr & 7)) * 8;

    f32x4 acc[4][4] = {};

    for (int k0 = 0; k0 < 1024; k0 += 64) {
        __syncthreads();
#pragma unroll
        for (int is = 0; is < 4; ++is) {
            gload_lds16(&A[(bm + sr + is * 32) * 1024 + k0 + scu * 8], &As[is * 2048 + tid * 8]);
            gload_lds16(&B[(bn + sr + is * 32) * 1024 + k0 + scu * 8], &Bs[is * 2048 + tid * 8]);
        }
        __syncthreads();
        f16x8 af0[4], af1[4], bf0[4], bf1[4];
#pragma unroll
        for (int mt = 0; mt < 4; ++mt) {
            int r = wm * 64 + mt * 16 + fr;
            af0[mt] = *(const f16x8*)&As[r * 64 + u0];
            af1[mt] = *(const f16x8*)&As[r * 64 + u1];
        }
#pragma unroll
        for (int nt = 0; nt < 4; ++nt) {
            int r = wn * 64 + nt * 16 + fr;
            bf0[nt] = *(const f16x8*)&Bs[r * 64 + u0];
            bf1[nt] = *(const f16x8*)&Bs[r * 64 + u1];
        }
#pragma unroll
        for (int mt = 0; mt < 4; ++mt)
#pragma unroll
            for (int nt = 0; nt < 4; ++nt) {
                acc[mt][nt] = MFMA16(af0[mt], bf0[nt], acc[mt][nt]);
                acc[mt][nt] = MFMA16(af1[mt], bf1[nt], acc[mt][nt]);
            }
    }

#pragma unroll
    for (int mt = 0; mt < 4; ++mt)
#pragma unroll
        for (int nt = 0; nt < 4; ++nt)
#pragma unroll
            for (int i = 0; i < 4; ++i) {
                int row = bm + wm * 64 + mt * 16 + fq * 4 + i;  // (s*2+b)
                int col = bn + wn * 64 + nt * 16 + fr;          // e in [0,3072)
                int s = row >> 1, b = row & 1;
                int which = col >> 10, rem = col & 1023;
                int h = rem >> 6, dk = rem & 63;
                int bh = b * 16 + h;
                float va = acc[mt][nt][i];
                if (which == 0)      outq[(bh * 2048 + s) * 64 + dk] = (f16)(va * QSCALE);
                else if (which == 1) outk[(bh * 2048 + s) * 64 + dk] = (f16)va;
                else                 outv[(bh * 2048 + s) * 64 + dk] = (f16)va;
            }
}

// ---------------- V transpose: [bh][s][dk] -> [bh][dk][s] ----------------
__global__ __launch_bounds__(256) void transpose_v(const f16* __restrict__ v, f16* __restrict__ vt) {
    __shared__ f16 T[64 * 72];
    const int tid = threadIdx.x;
    const int bh = blockIdx.y;
    const int s0 = blockIdx.x * 64;
    const f16* V = v + (bh * 2048 + s0) * 64;
    const int u = tid & 7;
#pragma unroll
    for (int hh = 0; hh < 2; ++hh) {
        int r = (tid >> 3) + hh * 32;   // s-local
        *(f16x8*)&T[r * 72 + u * 8] = *(const f16x8*)&V[r * 64 + u * 8];
    }
    __syncthreads();
#pragma unroll
    for (int o = 0; o < 2; ++o) {
        int dk = (tid >> 3) + o * 32;
        f16x8 val;
#pragma unroll
        for (int j = 0; j < 8; ++j) val[j] = T[(u * 8 + j) * 72 + dk];
        *(f16x8*)&vt[(bh * 64 + dk) * 2048 + s0 + u * 8] = val;
    }
}

// ---------------- Flash attention (causal, no-max softmax), 32x32 MFMA ----------------
// R5 block structure + R7 compute: block = 4 waves; waves 0,1 = tile A (qpair),
// waves 2,3 = tile B (31-qpair), 32 q-rows/wave; ONE shared double-buffered K/V
// stream of nB = 32-qpair chunks (A-waves idle at barriers after qpair+1 chunks).
// S^T = K·Q^T; P^T -> PV B-operand via pack+shfl_xor(32); O^T = VT·P^T.
// Q pre-scaled by 0.125*log2e so p = exp2(sc) directly.
__global__ __launch_bounds__(256) void attn_kernel(
    const f16* __restrict__ qg, const f16* __restrict__ kg,
    const f16* __restrict__ vtg, f16* __restrict__ attn)
{
    __shared__ f16 Ks[2][64 * 64];
    __shared__ f16 Vs[2][64 * 64];
    const int tid = threadIdx.x;            // 0..255
    const int lane = tid & 63;
    const int wave = tid >> 6;              // 0..3
    const int qpair = blockIdx.x;           // 0..15 (qpair=0 stages most -> dispatched first)
    const int bh = blockIdx.y;
    const int b = bh >> 4, h = bh & 15;
    const int col = lane & 31;              // q-local (C col)
    const int H = lane >> 5;                // wave half
    const int tsel = wave >> 1;             // 0 = tile A(qpair), 1 = tile B(31-qpair)
    const int qb = tsel ? (31 - qpair) : qpair;
    const int qrow0 = qb * 64 + (wave & 1) * 32;
    const int qmax = qrow0 + 31;
    const int ncw = qb + 1;                 // chunks this wave computes
    const int ncB = 32 - qpair;             // chunks staged by the block

    const f16* Q  = qg  + bh * 2048 * 64;
    const f16* K  = kg  + bh * 2048 * 64;
    const f16* VT = vtg + bh * 64 * 2048;

    const int sr = tid >> 3;                // 0..31 staging row
    const int scu = (tid & 7) ^ (sr & 7);   // swizzled 16B-unit

    // Q as B-operand fragments: B[n=q=col][k = c*16 + H*8 + j]
    f16x8 qf[4];
#pragma unroll
    for (int c = 0; c < 4; ++c)
        qf[c] = *(const f16x8*)&Q[(qrow0 + col) * 64 + c * 16 + H * 8];

    f32x16 oT[2] = {};
    float li = 0.f;

    auto stage = [&](int kc, int buf) {
        const int kb = kc * 64;
        gload_lds16(&K[(kb + sr) * 64 + scu * 8],         &Ks[buf][tid * 8]);
        gload_lds16(&K[(kb + sr + 32) * 64 + scu * 8],    &Ks[buf][2048 + tid * 8]);
        gload_lds16(&VT[sr * 2048 + kb + scu * 8],        &Vs[buf][tid * 8]);
        gload_lds16(&VT[(sr + 32) * 2048 + kb + scu * 8], &Vs[buf][2048 + tid * 8]);
    };

    stage(0, 0);
    for (int kc = 0; kc < ncB; ++kc) {
        const int kb = kc * 64;
        const int cur = kc & 1;
        __syncthreads();
        if (kc + 1 < ncB) stage(kc + 1, cur ^ 1);
        if (kc >= ncw) continue;            // A-waves done: wait at next barrier
        const f16* Kb = Ks[cur];
        const f16* Vb = Vs[cur];

#pragma unroll
        for (int kt = 0; kt < 2; ++kt) {
            const int kt0 = kb + kt * 32;
            if (kt0 > qmax) continue;       // tile fully masked (wave-uniform)

            // S^T tile: rows=keys kt0..kt0+31, cols=q (already in log2 domain)
            f32x16 sc = {};
#pragma unroll
            for (int c = 0; c < 4; ++c) {
                int r = kt * 32 + col;
                f16x8 ak = *(const f16x8*)&Kb[r * 64 + (((c * 2 + H) ^ (r & 7)) * 8)];
                sc = MFMA32(ak, qf[c], sc);
            }
            if (kt0 + 31 > qrow0) {         // partial causal mask
                int q = qrow0 + col;
#pragma unroll
                for (int r = 0; r < 16; ++r) {
                    int key = kt0 + (r & 3) + 8 * (r >> 2) + 4 * H;
                    if (key > q) sc[r] = -1e30f;
                }
            }
            // exp2 + li partials
#pragma unroll
            for (int r = 0; r < 16; ++r) {
                float p = __builtin_amdgcn_exp2f(sc[r]);
                li += p;
                sc[r] = p;
            }
            // pack + cross-half exchange -> PV B-fragments
            int pk[8], xk[8];
#pragma unroll
            for (int g = 0; g < 8; ++g) pk[g] = pk2(sc[2 * g], sc[2 * g + 1]);
#pragma unroll
            for (int g = 0; g < 8; ++g) xk[g] = __shfl_xor(pk[g], 32);
#pragma unroll
            for (int c2 = 0; c2 < 2; ++c2) {
                i32x4 bi;
                bi.x = H ? xk[4 * c2 + 2] : pk[4 * c2];
                bi.y = H ? xk[4 * c2 + 3] : pk[4 * c2 + 1];
                bi.z = H ? pk[4 * c2 + 2] : xk[4 * c2];
                bi.w = H ? pk[4 * c2 + 3] : xk[4 * c2 + 1];
                f16x8 pb = __builtin_bit_cast(f16x8, bi);
                const int sub = kt * 2 + c2;
#pragma unroll
                for (int dt = 0; dt < 2; ++dt) {
                    int rv = dt * 32 + col;
                    f16x8 av = *(const f16x8*)&Vb[rv * 64 + (((sub * 2 + H) ^ (rv & 7)) * 8)];
                    oT[dt] = MFMA32(av, pb, oT[dt]);
                }
            }
        }
    }

    // epilogue: li(q) spread across lane pair (col, col+32)
    li += __shfl_xor(li, 32);
    float inv = __builtin_amdgcn_rcpf(li);
    const int q = qrow0 + col;
    f16* dst = &attn[(q * 2 + b) * 1024 + h * 64];
#pragma unroll
    for (int dt = 0; dt < 2; ++dt)
#pragma unroll
        for (int g = 0; g < 4; ++g) {
            f16x4 pv = {(f16)(oT[dt][4 * g] * inv),     (f16)(oT[dt][4 * g + 1] * inv),
                        (f16)(oT[dt][4 * g + 2] * inv), (f16)(oT[dt][4 * g + 3] * inv)};
            *(f16x4*)&dst[dt * 32 + 8 * g + 4 * H] = pv;
        }
}

// ---------------- Out GEMM: out[4096x1024] = A[4096x1024] * Wout^T + bias ----------------
__global__ __launch_bounds__(256) void gemm_out(
    const f16* __restrict__ A, const f16* __restrict__ B,
    const float* __restrict__ bias, float* __restrict__ out)
{
    __shared__ f16 As[128 * 64];
    __shared__ f16 Bs[64 * 64];
    const int tid = threadIdx.x;
    const int lane = tid & 63;
    const int wave = tid >> 6;
    const int wm = wave >> 1, wn = wave & 1;
    const int bm = blockIdx.y * 128, bn = blockIdx.x * 64;
    const int sr = tid >> 3;
    const int scu = (tid & 7) ^ (sr & 7);
    const int fr = lane & 15, fq = lane >> 4;
    const int u0 = (fq ^ (fr & 7)) * 8;
    const int u1 = ((4 + fq) ^ (fr & 7)) * 8;

    f32x4 acc[4][2] = {};

    for (int k0 = 0; k0 < 1024; k0 += 64) {
        __syncthreads();
#pragma unroll
        for (int is = 0; is < 4; ++is)
            gload_lds16(&A[(bm + sr + is * 32) * 1024 + k0 + scu * 8], &As[is * 2048 + tid * 8]);
#pragma unroll
        for (int is = 0; is < 2; ++is)
            gload_lds16(&B[(bn + sr + is * 32) * 1024 + k0 + scu * 8], &Bs[is * 2048 + tid * 8]);
        __syncthreads();
        f16x8 af0[4], af1[4], bf0[2], bf1[2];
#pragma unroll
        for (int mt = 0; mt < 4; ++mt) {
            int r = wm * 64 + mt * 16 + fr;
            af0[mt] = *(const f16x8*)&As[r * 64 + u0];
            af1[mt] = *(const f16x8*)&As[r * 64 + u1];
        }
#pragma unroll
        for (int nt = 0; nt < 2; ++nt) {
            int r = wn * 32 + nt * 16 + fr;
            bf0[nt] = *(const f16x8*)&Bs[r * 64 + u0];
            bf1[nt] = *(const f16x8*)&Bs[r * 64 + u1];
        }
#pragma unroll
        for (int mt = 0; mt < 4; ++mt)
#pragma unroll
            for (int nt = 0; nt < 2; ++nt) {
                acc[mt][nt] = MFMA16(af0[mt], bf0[nt], acc[mt][nt]);
                acc[mt][nt] = MFMA16(af1[mt], bf1[nt], acc[mt][nt]);
            }
    }

#pragma unroll
    for (int mt = 0; mt < 4; ++mt)
#pragma unroll
        for (int nt = 0; nt < 2; ++nt)
#pragma unroll
            for (int i = 0; i < 4; ++i) {
                int row = bm + wm * 64 + mt * 16 + fq * 4 + i;
                int col = bn + wn * 32 + nt * 16 + fr;
                out[row * 1024 + col] = acc[mt][nt][i] + bias[col];
            }
}

extern "C" void kernel_launch(void* const* d_in, const int* in_sizes, int n_in,
                              void* d_out, int out_size, void* d_ws, size_t ws_size,
                              hipStream_t stream)
{
    const float* x     = (const float*)d_in[0];
    const float* w_qkv = (const float*)d_in[1];
    const float* w_out = (const float*)d_in[2];
    const float* b_out = (const float*)d_in[3];
    float* out = (float*)d_out;

    char* ws = (char*)d_ws;
    f16* xh  = (f16*)(ws);              // dead after gemm_qkv
    f16* vt  = (f16*)(ws);              // reuses xh space
    f16* wqh = (f16*)(ws + 8388608);
    f16* woh = (f16*)(ws + 14680064);
    f16* qh  = (f16*)(ws + 16777216);
    f16* kh  = (f16*)(ws + 25165824);
    f16* vh  = (f16*)(ws + 33554432);
    f16* ah  = (f16*)(ws + 41943040);

    cast_all<<<8192, 256, 0, stream>>>(x, w_qkv, w_out, xh);
    gemm_qkv<<<dim3(24, 32), 256, 0, stream>>>(xh, wqh, qh, kh, vh);
    transpose_v<<<dim3(32, 32), 256, 0, stream>>>(vh, vt);
    attn_kernel<<<dim3(16, 32), 256, 0, stream>>>(qh, kh, vt, ah);
    gemm_out<<<dim3(16, 32), 256, 0, stream>>>(ah, woh, b_out, out);
}

// Round 9
// 185.756 us; speedup vs baseline: 1.1601x; 1.1117x over previous
//
#include <hip/hip_runtime.h>
#include <cstdint>

typedef _Float16 f16;
typedef _Float16 f16x4 __attribute__((ext_vector_type(4)));
typedef _Float16 f16x8 __attribute__((ext_vector_type(8)));
typedef float f32x4 __attribute__((ext_vector_type(4)));

#define MFMA16(a, b, c) __builtin_amdgcn_mfma_f32_16x16x32_f16(a, b, c, 0, 0, 0)
#define QSCALE 0.1803368801111243f  /* 0.125 * log2(e): scores land in log2 domain */

// direct global->LDS 16B async copy (m97 pattern)
__device__ __forceinline__ void gload_lds16(const void* g, void* l) {
    __builtin_amdgcn_global_load_lds((__attribute__((address_space(1))) void*)(g),
                                     (__attribute__((address_space(3))) void*)(l),
                                     16, 0, 0);
}

// Problem constants: S=2048, B=2, D=1024, H=16, DK=64
// ws layout (bytes):
//  xh   @ 0         : 4096x1024 f16 = 8 MB       (dead after gemm_qkv)
//  wqh  @ 8388608   : 3072x1024 f16 = 6 MB
//  woh  @ 14680064  : 1024x1024 f16 = 2 MB
//  qh   @ 16777216  : [32][2048][64] f16 = 8 MB  (PRE-SCALED by 0.125*log2e)
//  kh   @ 25165824  : [32][2048][64] f16 = 8 MB
//  vt   @ 33554432  : [32][64][2048] f16 = 8 MB  (V transposed, written by gemm_qkv)
//  ah   @ 41943040  : [4096][1024] f16 = 8 MB

// Single fused cast: outputs are contiguous in ws (xh | wqh | woh).
__global__ void cast_all(const float* __restrict__ x, const float* __restrict__ wqv,
                         const float* __restrict__ wo, f16* __restrict__ out) {
    int i = blockIdx.x * blockDim.x + threadIdx.x;  // 0..2097151 float4s
    const float* src; int li;
    if (i < 1048576)      { src = x;   li = i; }
    else if (i < 1835008) { src = wqv; li = i - 1048576; }
    else                  { src = wo;  li = i - 1835008; }
    float4 v = reinterpret_cast<const float4*>(src)[li];
    f16x4 o = {(f16)v.x, (f16)v.y, (f16)v.z, (f16)v.w};
    reinterpret_cast<f16x4*>(out)[i] = o;
}

// ---------------- QKV GEMM: C[4096x3072] = X[4096x1024] * Wqkv^T ----------------
// BK=64, XOR-swizzled 16B units. Epilogue: per-block uniform target (blocks never
// straddle Q/K/V col ranges); V-blocks transpose in dead staging LDS -> vt direct.
__global__ __launch_bounds__(256) void gemm_qkv(
    const f16* __restrict__ A, const f16* __restrict__ B,
    f16* __restrict__ outq, f16* __restrict__ outk, f16* __restrict__ outvt)
{
    __shared__ f16 SM[128 * 64 * 2];        // As | Bs; reused as Ts in V epilogue
    f16* As = SM;
    f16* Bs = SM + 8192;
    const int tid = threadIdx.x;
    const int lane = tid & 63;
    const int wave = tid >> 6;
    const int wm = wave >> 1, wn = wave & 1;
    const int bm = blockIdx.y * 128, bn = blockIdx.x * 128;
    const int sr = tid >> 3;                 // staging row 0..31 (per 32-row issue)
    const int scu = (tid & 7) ^ (sr & 7);    // swizzled global 16B-unit
    const int fr = lane & 15, fq = lane >> 4;
    const int u0 = (fq ^ (fr & 7)) * 8;
    const int u1 = ((4 + fq) ^ (fr & 7)) * 8;

    f32x4 acc[4][4] = {};

    for (int k0 = 0; k0 < 1024; k0 += 64) {
        __syncthreads();
#pragma unroll
        for (int is = 0; is < 4; ++is) {
            gload_lds16(&A[(bm + sr + is * 32) * 1024 + k0 + scu * 8], &As[is * 2048 + tid * 8]);
            gload_lds16(&B[(bn + sr + is * 32) * 1024 + k0 + scu * 8], &Bs[is * 2048 + tid * 8]);
        }
        __syncthreads();
        f16x8 af0[4], af1[4], bf0[4], bf1[4];
#pragma unroll
        for (int mt = 0; mt < 4; ++mt) {
            int r = wm * 64 + mt * 16 + fr;
            af0[mt] = *(const f16x8*)&As[r * 64 + u0];
            af1[mt] = *(const f16x8*)&As[r * 64 + u1];
        }
#pragma unroll
        for (int nt = 0; nt < 4; ++nt) {
            int r = wn * 64 + nt * 16 + fr;
            bf0[nt] = *(const f16x8*)&Bs[r * 64 + u0];
            bf1[nt] = *(const f16x8*)&Bs[r * 64 + u1];
        }
#pragma unroll
        for (int mt = 0; mt < 4; ++mt)
#pragma unroll
            for (int nt = 0; nt < 4; ++nt) {
                acc[mt][nt] = MFMA16(af0[mt], bf0[nt], acc[mt][nt]);
                acc[mt][nt] = MFMA16(af1[mt], bf1[nt], acc[mt][nt]);
            }
    }

    const int x = blockIdx.x;
    if (x < 16) {
        // Q (x<8) or K block: uniform target, row-layout [bh][s][64]
        f16* base = (x < 8) ? outq : outk;
        const float scale = (x < 8) ? QSCALE : 1.0f;
        const int coloff = (x < 8) ? bn : (bn - 1024);
#pragma unroll
        for (int mt = 0; mt < 4; ++mt)
#pragma unroll
            for (int nt = 0; nt < 4; ++nt)
#pragma unroll
                for (int i = 0; i < 4; ++i) {
                    int row = bm + wm * 64 + mt * 16 + fq * 4 + i;  // (s*2+b)
                    int col = coloff + wn * 64 + nt * 16 + fr;      // 0..1023
                    int s = row >> 1, b = row & 1;
                    int h = col >> 6, dk = col & 63;
                    base[((b * 16 + h) * 2048 + s) * 64 + dk] = (f16)(acc[mt][nt][i] * scale);
                }
    } else {
        // V block: LDS transpose (2 passes over wn halves) -> vt[bh][dk][s]
        const int xb = x - 16;              // 0..7
        const int s0 = bm >> 1;             // 64-aligned s base
        f16* Ts = SM;                        // [128][76] = 9728 f16 (fits in SM)
#pragma unroll
        for (int p = 0; p < 2; ++p) {
            __syncthreads();
            if (wn == p) {
#pragma unroll
                for (int mt = 0; mt < 4; ++mt)
#pragma unroll
                    for (int nt = 0; nt < 4; ++nt)
#pragma unroll
                        for (int i = 0; i < 4; ++i) {
                            int row = wm * 64 + mt * 16 + fq * 4 + i;  // 0..127 local
                            int cl = nt * 16 + fr;                     // 0..63 local col
                            Ts[(cl * 2 + (row & 1)) * 76 + (row >> 1)] = (f16)acc[mt][nt][i];
                        }
            }
            __syncthreads();
            const int h = xb * 2 + p;
            const int sj = tid & 7;
#pragma unroll
            for (int it = 0; it < 4; ++it) {
                int idx = (tid >> 3) + it * 32;     // 0..127
                int bsel = idx & 1, dk = idx >> 1;  // b, dk(=cl)
                f16x8 v = *(const f16x8*)&Ts[(dk * 2 + bsel) * 76 + sj * 8];
                *(f16x8*)&outvt[((bsel * 16 + h) * 64 + dk) * 2048 + s0 + sj * 8] = v;
            }
        }
    }
}

// ---------------- Flash attention (causal, no-max softmax) — R5 structure ----------------
// Block = 4 waves; each wave computes 16 rows of tile B(31-qpair) then 16 rows of
// tile A(qpair) per chunk (wave-serial = ILP). One shared double-buffered K/V stream
// of nB = 32-qpair chunks. Q pre-scaled by 0.125*log2e -> p = exp2(sc) directly.
__global__ __launch_bounds__(256) void attn_kernel(
    const f16* __restrict__ qg, const f16* __restrict__ kg,
    const f16* __restrict__ vtg, f16* __restrict__ attn)
{
    __shared__ f16 Ks[2][64 * 64];
    __shared__ f16 Vs[2][64 * 64];
    __shared__ f16 plds[4][16 * 72];
    const int tid = threadIdx.x;
    const int lane = tid & 63;
    const int wave = tid >> 6;
    const int qpair = blockIdx.x;   // 0..15 (qpair=0 stages most, dispatched first)
    const int bh = blockIdx.y;
    const int b = bh >> 4, h = bh & 15;
    const int fr = lane & 15, fq = lane >> 4;

    const int bqA = qpair * 64;
    const int bqB = (31 - qpair) * 64;
    const int nA = qpair + 1;
    const int nB = 32 - qpair;
    const int qrowA = bqA + wave * 16;
    const int qrowB = bqB + wave * 16;

    const f16* Q  = qg  + bh * 2048 * 64;
    const f16* K  = kg  + bh * 2048 * 64;
    const f16* VT = vtg + bh * 64 * 2048;
    f16* P = plds[wave];

    const int sr = tid >> 3;
    const int scu = (tid & 7) ^ (sr & 7);

    f16x8 aqA0 = *(const f16x8*)&Q[(qrowA + fr) * 64 + fq * 8];
    f16x8 aqA1 = *(const f16x8*)&Q[(qrowA + fr) * 64 + 32 + fq * 8];
    f16x8 aqB0 = *(const f16x8*)&Q[(qrowB + fr) * 64 + fq * 8];
    f16x8 aqB1 = *(const f16x8*)&Q[(qrowB + fr) * 64 + 32 + fq * 8];

    f32x4 oA[4] = {}, oB[4] = {};
    float lA[4] = {}, lB[4] = {};

    auto stage = [&](int kc, int buf) {
        const int kb = kc * 64;
        gload_lds16(&K[(kb + sr) * 64 + scu * 8],         &Ks[buf][tid * 8]);
        gload_lds16(&K[(kb + sr + 32) * 64 + scu * 8],    &Ks[buf][2048 + tid * 8]);
        gload_lds16(&VT[sr * 2048 + kb + scu * 8],        &Vs[buf][tid * 8]);
        gload_lds16(&VT[(sr + 32) * 2048 + kb + scu * 8], &Vs[buf][2048 + tid * 8]);
    };

    auto compute = [&](const f16x8& aq0, const f16x8& aq1, int qrow0, int kb,
                       const f16* Ksb, const f16* Vsb, f32x4* oacc, float* li, bool domask) {
        f32x4 sc[4] = {};
#pragma unroll
        for (int ct = 0; ct < 4; ++ct) {
            int r = ct * 16 + fr;
            f16x8 b0 = *(const f16x8*)&Ksb[r * 64 + ((fq ^ (r & 7)) * 8)];
            f16x8 b1 = *(const f16x8*)&Ksb[r * 64 + (((4 + fq) ^ (r & 7)) * 8)];
            sc[ct] = MFMA16(aq0, b0, sc[ct]);
            sc[ct] = MFMA16(aq1, b1, sc[ct]);
        }
        if (domask) {
#pragma unroll
            for (int ct = 0; ct < 4; ++ct) {
                int kcol = kb + ct * 16 + fr;
#pragma unroll
                for (int i = 0; i < 4; ++i)
                    if (kcol > qrow0 + fq * 4 + i) sc[ct][i] = -1e30f;
            }
        }
#pragma unroll
        for (int i = 0; i < 4; ++i) {
            float p0 = __builtin_amdgcn_exp2f(sc[0][i]);
            float p1 = __builtin_amdgcn_exp2f(sc[1][i]);
            float p2 = __builtin_amdgcn_exp2f(sc[2][i]);
            float p3 = __builtin_amdgcn_exp2f(sc[3][i]);
            li[i] += (p0 + p1) + (p2 + p3);
            P[(fq * 4 + i) * 72 + fr]      = (f16)p0;
            P[(fq * 4 + i) * 72 + 16 + fr] = (f16)p1;
            P[(fq * 4 + i) * 72 + 32 + fr] = (f16)p2;
            P[(fq * 4 + i) * 72 + 48 + fr] = (f16)p3;
        }
        f16x8 ap0 = *(const f16x8*)&P[fr * 72 + fq * 8];
        f16x8 ap1 = *(const f16x8*)&P[fr * 72 + 32 + fq * 8];
#pragma unroll
        for (int nt = 0; nt < 4; ++nt) {
            int dk = nt * 16 + fr;
            f16x8 bv0 = *(const f16x8*)&Vsb[dk * 64 + ((fq ^ (dk & 7)) * 8)];
            f16x8 bv1 = *(const f16x8*)&Vsb[dk * 64 + (((4 + fq) ^ (dk & 7)) * 8)];
            oacc[nt] = MFMA16(ap0, bv0, oacc[nt]);
            oacc[nt] = MFMA16(ap1, bv1, oacc[nt]);
        }
    };

    stage(0, 0);
    for (int kc = 0; kc < nB; ++kc) {
        const int kb = kc * 64;
        const int cur = kc & 1;
        __syncthreads();
        if (kc + 1 < nB) stage(kc + 1, cur ^ 1);
        compute(aqB0, aqB1, qrowB, kb, Ks[cur], Vs[cur], oB, lB, kb + 63 > qrowB);
        if (kc < nA)
            compute(aqA0, aqA1, qrowA, kb, Ks[cur], Vs[cur], oA, lA, kb + 63 > qrowA);
    }

#pragma unroll
    for (int i = 0; i < 4; ++i) {
        float rs = lA[i];
        rs += __shfl_xor(rs, 1);
        rs += __shfl_xor(rs, 2);
        rs += __shfl_xor(rs, 4);
        rs += __shfl_xor(rs, 8);
        float inv = __builtin_amdgcn_rcpf(rs);
        int srow = qrowA + fq * 4 + i;
#pragma unroll
        for (int nt = 0; nt < 4; ++nt)
            attn[(srow * 2 + b) * 1024 + h * 64 + nt * 16 + fr] = (f16)(oA[nt][i] * inv);
    }
#pragma unroll
    for (int i = 0; i < 4; ++i) {
        float rs = lB[i];
        rs += __shfl_xor(rs, 1);
        rs += __shfl_xor(rs, 2);
        rs += __shfl_xor(rs, 4);
        rs += __shfl_xor(rs, 8);
        float inv = __builtin_amdgcn_rcpf(rs);
        int srow = qrowB + fq * 4 + i;
#pragma unroll
        for (int nt = 0; nt < 4; ++nt)
            attn[(srow * 2 + b) * 1024 + h * 64 + nt * 16 + fr] = (f16)(oB[nt][i] * inv);
    }
}

// ---------------- Out GEMM: out[4096x1024] = A[4096x1024] * Wout^T + bias ----------------
__global__ __launch_bounds__(256) void gemm_out(
    const f16* __restrict__ A, const f16* __restrict__ B,
    const float* __restrict__ bias, float* __restrict__ out)
{
    __shared__ f16 As[128 * 64];
    __shared__ f16 Bs[64 * 64];
    const int tid = threadIdx.x;
    const int lane = tid & 63;
    const int wave = tid >> 6;
    const int wm = wave >> 1, wn = wave & 1;
    const int bm = blockIdx.y * 128, bn = blockIdx.x * 64;
    const int sr = tid >> 3;
    const int scu = (tid & 7) ^ (sr & 7);
    const int fr = lane & 15, fq = lane >> 4;
    const int u0 = (fq ^ (fr & 7)) * 8;
    const int u1 = ((4 + fq) ^ (fr & 7)) * 8;

    f32x4 acc[4][2] = {};

    for (int k0 = 0; k0 < 1024; k0 += 64) {
        __syncthreads();
#pragma unroll
        for (int is = 0; is < 4; ++is)
            gload_lds16(&A[(bm + sr + is * 32) * 1024 + k0 + scu * 8], &As[is * 2048 + tid * 8]);
#pragma unroll
        for (int is = 0; is < 2; ++is)
            gload_lds16(&B[(bn + sr + is * 32) * 1024 + k0 + scu * 8], &Bs[is * 2048 + tid * 8]);
        __syncthreads();
        f16x8 af0[4], af1[4], bf0[2], bf1[2];
#pragma unroll
        for (int mt = 0; mt < 4; ++mt) {
            int r = wm * 64 + mt * 16 + fr;
            af0[mt] = *(const f16x8*)&As[r * 64 + u0];
            af1[mt] = *(const f16x8*)&As[r * 64 + u1];
        }
#pragma unroll
        for (int nt = 0; nt < 2; ++nt) {
            int r = wn * 32 + nt * 16 + fr;
            bf0[nt] = *(const f16x8*)&Bs[r * 64 + u0];
            bf1[nt] = *(const f16x8*)&Bs[r * 64 + u1];
        }
#pragma unroll
        for (int mt = 0; mt < 4; ++mt)
#pragma unroll
            for (int nt = 0; nt < 2; ++nt) {
                acc[mt][nt] = MFMA16(af0[mt], bf0[nt], acc[mt][nt]);
                acc[mt][nt] = MFMA16(af1[mt], bf1[nt], acc[mt][nt]);
            }
    }

#pragma unroll
    for (int mt = 0; mt < 4; ++mt)
#pragma unroll
        for (int nt = 0; nt < 2; ++nt)
#pragma unroll
            for (int i = 0; i < 4; ++i) {
                int row = bm + wm * 64 + mt * 16 + fq * 4 + i;
                int col = bn + wn * 32 + nt * 16 + fr;
                out[row * 1024 + col] = acc[mt][nt][i] + bias[col];
            }
}

extern "C" void kernel_launch(void* const* d_in, const int* in_sizes, int n_in,
                              void* d_out, int out_size, void* d_ws, size_t ws_size,
                              hipStream_t stream)
{
    const float* x     = (const float*)d_in[0];
    const float* w_qkv = (const float*)d_in[1];
    const float* w_out = (const float*)d_in[2];
    const float* b_out = (const float*)d_in[3];
    float* out = (float*)d_out;

    char* ws = (char*)d_ws;
    f16* xh  = (f16*)(ws);
    f16* wqh = (f16*)(ws + 8388608);
    f16* woh = (f16*)(ws + 14680064);
    f16* qh  = (f16*)(ws + 16777216);
    f16* kh  = (f16*)(ws + 25165824);
    f16* vt  = (f16*)(ws + 33554432);
    f16* ah  = (f16*)(ws + 41943040);

    cast_all<<<8192, 256, 0, stream>>>(x, w_qkv, w_out, xh);
    gemm_qkv<<<dim3(24, 32), 256, 0, stream>>>(xh, wqh, qh, kh, vt);
    attn_kernel<<<dim3(16, 32), 256, 0, stream>>>(qh, kh, vt, ah);
    gemm_out<<<dim3(16, 32), 256, 0, stream>>>(ah, woh, b_out, out);
}